// Round 5
// baseline (175.957 us; speedup 1.0000x reference)
//
#include <hip/hip_runtime.h>
#include <math.h>

#define NB 8192
#define ND 512
#define NPROTO 16
#define NBLK 256                   // k_norm grid
#define NSLOT 16                   // protoPart slot copies
#define TINV 14.285714285714286f   // 1/0.07

typedef short short8 __attribute__((ext_vector_type(8)));
typedef float float4v __attribute__((ext_vector_type(4)));

__device__ __forceinline__ unsigned short f2bf(float f) {
  unsigned u = __builtin_bit_cast(unsigned, f);
  unsigned r = (u + 0x7FFFu + ((u >> 16) & 1u)) >> 16;
  return (unsigned short)r;
}
__device__ __forceinline__ float bflo(unsigned u) {
  return __builtin_bit_cast(float, u << 16);
}
__device__ __forceinline__ float bfhi(unsigned u) {
  return __builtin_bit_cast(float, u & 0xFFFF0000u);
}

// ---- K1: wave-per-row normalize + bf16 store + slotted atomic seg sums ----
__global__ __launch_bounds__(512) void k_norm(
    const float* __restrict__ z, const float* __restrict__ attr,
    unsigned short* __restrict__ znb, float* __restrict__ protoPart,
    float* __restrict__ cntPart, int* __restrict__ code,
    int* __restrict__ validList, int* __restrict__ validCnt)
{
  __shared__ float acc[NPROTO * ND];   // 32 KB
  __shared__ float cnt[NPROTO];
  const int t = threadIdx.x, lane = t & 63, wid = t >> 6;
  for (int i = t; i < NPROTO * ND; i += 512) acc[i] = 0.f;
  if (t < NPROTO) cnt[t] = 0.f;
  __syncthreads();
  #pragma unroll
  for (int rr = 0; rr < 4; ++rr) {
    const int r = blockIdx.x * 32 + wid * 4 + rr;
    const float* zr = z + (size_t)r * ND;
    float v[8];
    #pragma unroll
    for (int jj = 0; jj < 8; ++jj) v[jj] = zr[lane + jj * 64];
    float s = 0.f;
    #pragma unroll
    for (int jj = 0; jj < 8; ++jj) s += v[jj] * v[jj];
    #pragma unroll
    for (int o = 32; o > 0; o >>= 1) s += __shfl_xor(s, o);
    const float inv = 1.f / fmaxf(sqrtf(s), 1e-12f);
    const float* a = attr + (size_t)r * 4;
    const int c = (a[0] > 0.5f ? 8 : 0) | (a[1] > 0.5f ? 4 : 0) |
                  (a[2] > 0.5f ? 2 : 0) | (a[3] > 0.5f ? 1 : 0);
    float* accRow = acc + c * ND;
    #pragma unroll
    for (int jj = 0; jj < 8; ++jj) {
      const float zv = v[jj] * inv;
      atomicAdd(&accRow[lane + jj * 64], zv);        // LDS, consecutive banks
      znb[(size_t)r * ND + lane + jj * 64] = f2bf(zv);
    }
    if (lane == 0) {
      code[r] = c;
      atomicAdd(&cnt[c], 1.f);
      if (c == NPROTO - 1) { int slot = atomicAdd(validCnt, 1); validList[slot] = r; }
    }
  }
  __syncthreads();
  const int slot = blockIdx.x & (NSLOT - 1);
  float* base = protoPart + (size_t)slot * (NPROTO * ND);
  for (int i = t; i < NPROTO * ND; i += 512) atomicAdd(&base[i], acc[i]);
  if (t < NPROTO) atomicAdd(&cntPart[slot * NPROTO + t], cnt[t]);
}

// ---- K2: 16 blocks x 512 thr: reduce 16 slots + normalize -----------------
__global__ __launch_bounds__(512) void k_protonorm(
    const float* __restrict__ protoPart, const float* __restrict__ cntPart,
    float* __restrict__ protos)
{
  __shared__ float red[8];
  __shared__ float cSh;
  const int t = threadIdx.x, lane = t & 63, wid = t >> 6;
  const int p = blockIdx.x;
  float s = 0.f;
  #pragma unroll
  for (int b = 0; b < NSLOT; ++b)
    s += protoPart[((size_t)b * NPROTO + p) * ND + t];
  if (t < 64) {
    float c = (t < NSLOT) ? cntPart[t * NPROTO + p] : 0.f;
    c += __shfl_xor(c, 1);
    c += __shfl_xor(c, 2);
    c += __shfl_xor(c, 4);
    c += __shfl_xor(c, 8);
    if (t == 0) cSh = c;
  }
  __syncthreads();
  const float cTot = cSh;
  const float mean = s / fmaxf(cTot, 1.f);
  float sq = mean * mean;
  #pragma unroll
  for (int o = 32; o > 0; o >>= 1) sq += __shfl_xor(sq, o);
  if (lane == 0) red[wid] = sq;
  __syncthreads();
  const float sum = red[0]+red[1]+red[2]+red[3]+red[4]+red[5]+red[6]+red[7];
  const float scale = (cTot > 0.f) ? 1.f / fmaxf(sqrtf(sum), 1e-12f) : 0.f;
  protos[p * ND + t] = mean * scale;
}

// ---- K3: prototype contrastive loss (bf16 reads) --------------------------
#define PLD (ND + 4)
__global__ __launch_bounds__(256) void k_protoloss(
    const unsigned short* __restrict__ znb, const float* __restrict__ protos,
    const int* __restrict__ code, float* __restrict__ protoLossAcc)
{
  __shared__ float pl[NPROTO * PLD];
  const int t = threadIdx.x;
  for (int i = t; i < NPROTO * ND; i += 256)
    pl[(i >> 9) * PLD + (i & 511)] = protos[i];
  __syncthreads();
  const int lane = t & 63, wid = t >> 6;
  const int p = lane & 15, grp = lane >> 4;
  float lacc = 0.f;
  for (int r = blockIdx.x * 4 + wid; r < NB; r += gridDim.x * 4) {
    const uint4* zr = (const uint4*)(znb + (size_t)r * ND + grp * 128);
    const float* pb = &pl[p * PLD + grp * 128];
    float s = 0.f;
    #pragma unroll
    for (int it = 0; it < 16; ++it) {
      const uint4 u = zr[it];
      const float4 p0 = *(const float4*)(pb + it * 8);
      const float4 p1 = *(const float4*)(pb + it * 8 + 4);
      s += bflo(u.x)*p0.x + bfhi(u.x)*p0.y + bflo(u.y)*p0.z + bfhi(u.y)*p0.w;
      s += bflo(u.z)*p1.x + bfhi(u.z)*p1.y + bflo(u.w)*p1.z + bfhi(u.w)*p1.w;
    }
    s += __shfl_xor(s, 16);
    s += __shfl_xor(s, 32);
    const float e = __expf(s * TINV);
    float alls = e;
    alls += __shfl_xor(alls, 1);
    alls += __shfl_xor(alls, 2);
    alls += __shfl_xor(alls, 4);
    alls += __shfl_xor(alls, 8);
    const int c = code[r];
    const float pos = __shfl(e, (lane & ~15) | c);
    if (lane == 0) lacc += -logf(pos / fmaxf(alls, 1e-8f) + 1e-8f);
  }
  if (lane == 0) atomicAdd(protoLossAcc, lacc);
}

// ---- K4: pairwise bf16 MFMA GEMM, reg-staged pipeline, fused finalize -----
__global__ __launch_bounds__(256) void k_pairwise(
    const unsigned short* __restrict__ znb,
    const int* __restrict__ code, const int* __restrict__ validList,
    const int* __restrict__ validCnt,
    float* __restrict__ sAllG, float* __restrict__ sPosG,
    float* __restrict__ protoLossAcc, unsigned* __restrict__ doneCnt,
    float* __restrict__ out)
{
  __shared__ __align__(16) unsigned short aT[64 * 64];    // 8 KB, swizzled
  __shared__ __align__(16) unsigned short bT[128 * 64];   // 16 KB, swizzled
  __shared__ int rowIdx[64];
  __shared__ unsigned char aoSh[128];
  __shared__ bool isLast;
  __shared__ float red[8];
  const int t = threadIdx.x, lane = t & 63, wid = t >> 6;
  const int ww = wid & 1, wv = wid >> 1;
  const int m = validCnt[0];
  const int nIT = (m + 63) >> 6;
  const int items = nIT * 64;
  const int grp = lane >> 4, cl = lane & 15;
  const int ia = t >> 2;                      // A-stage row 0..63
  const int jB[4] = { (t+0) >> 3, (t+256) >> 3, (t+512) >> 3, (t+768) >> 3 };
  const int kqB[4] = { t & 7, t & 7, t & 7, t & 7 };
  for (int wi = blockIdx.x; wi < items; wi += gridDim.x) {
    const int i0 = (wi >> 6) * 64;
    const int jb = (wi & 63) * 128;
    __syncthreads();
    if (t < 64) rowIdx[t] = (i0 + t < m) ? validList[i0 + t] : -1;
    if (t < 128) aoSh[t] = (code[jb + t] == NPROTO - 1) ? 1 : 0;
    __syncthreads();
    const int riA = rowIdx[ia];
    const int srowA = (riA < 0) ? 0 : riA;
    float4v acc[2][4];
    #pragma unroll
    for (int mi = 0; mi < 2; ++mi)
      #pragma unroll
      for (int nj = 0; nj < 4; ++nj) acc[mi][nj] = (float4v)(0.f);
    // prefetch kc=0
    uint4 aR[2], bR[4];
    #pragma unroll
    for (int h = 0; h < 2; ++h)
      aR[h] = *(const uint4*)(znb + (size_t)srowA * ND + ((t & 3) + h * 4) * 8);
    #pragma unroll
    for (int h = 0; h < 4; ++h)
      bR[h] = *(const uint4*)(znb + (size_t)(jb + jB[h]) * ND + kqB[h] * 8);
    #pragma unroll
    for (int kc = 0; kc < 8; ++kc) {
      __syncthreads();                        // LDS consumed from prev kc
      #pragma unroll
      for (int h = 0; h < 2; ++h) {
        const int kq = (t & 3) + h * 4;
        *(uint4*)((char*)aT + ia * 128 + ((kq * 16) ^ ((ia & 7) << 4))) = aR[h];
      }
      #pragma unroll
      for (int h = 0; h < 4; ++h)
        *(uint4*)((char*)bT + jB[h] * 128 + ((kqB[h] * 16) ^ ((jB[h] & 7) << 4))) = bR[h];
      uint4 aN[2], bN[4];
      if (kc < 7) {                            // issue next-chunk loads early
        const int k0 = (kc + 1) * 64;
        #pragma unroll
        for (int h = 0; h < 2; ++h)
          aN[h] = *(const uint4*)(znb + (size_t)srowA * ND + k0 + ((t & 3) + h * 4) * 8);
        #pragma unroll
        for (int h = 0; h < 4; ++h)
          bN[h] = *(const uint4*)(znb + (size_t)(jb + jB[h]) * ND + k0 + kqB[h] * 8);
      }
      __syncthreads();
      #pragma unroll
      for (int ks = 0; ks < 2; ++ks) {
        const int kb = ks * 64 + grp * 16;
        short8 af[2], bf[4];
        #pragma unroll
        for (int mi = 0; mi < 2; ++mi) {
          const int rw = wv * 32 + mi * 16 + cl;
          af[mi] = *(const short8*)((char*)aT + rw * 128 + (kb ^ ((rw & 7) << 4)));
        }
        #pragma unroll
        for (int nj = 0; nj < 4; ++nj) {
          const int rw = ww * 64 + nj * 16 + cl;
          bf[nj] = *(const short8*)((char*)bT + rw * 128 + (kb ^ ((rw & 7) << 4)));
        }
        #pragma unroll
        for (int mi = 0; mi < 2; ++mi)
          #pragma unroll
          for (int nj = 0; nj < 4; ++nj)
            acc[mi][nj] = __builtin_amdgcn_mfma_f32_16x16x32_bf16(af[mi], bf[nj], acc[mi][nj], 0, 0, 0);
      }
      #pragma unroll
      for (int h = 0; h < 2; ++h) aR[h] = aN[h];
      #pragma unroll
      for (int h = 0; h < 4; ++h) bR[h] = bN[h];
    }
    // epilogue: exp, diag+pos masks, row sums, atomics
    #pragma unroll
    for (int mi = 0; mi < 2; ++mi) {
      float sA[4] = {0.f, 0.f, 0.f, 0.f}, sP[4] = {0.f, 0.f, 0.f, 0.f};
      int ri[4];
      #pragma unroll
      for (int q = 0; q < 4; ++q) ri[q] = rowIdx[wv * 32 + mi * 16 + grp * 4 + q];
      #pragma unroll
      for (int nj = 0; nj < 4; ++nj) {
        const int jl = ww * 64 + nj * 16 + cl;
        const int jg = jb + jl;
        const float ao = aoSh[jl] ? 1.f : 0.f;
        #pragma unroll
        for (int q = 0; q < 4; ++q) {
          float e = __expf(acc[mi][nj][q] * TINV);
          e = (jg == ri[q]) ? 0.f : e;
          sA[q] += e;
          sP[q] += e * ao;
        }
      }
      #pragma unroll
      for (int q = 0; q < 4; ++q) {
        #pragma unroll
        for (int o = 1; o < 16; o <<= 1) {
          sA[q] += __shfl_xor(sA[q], o);
          sP[q] += __shfl_xor(sP[q], o);
        }
      }
      if (cl == 0) {
        #pragma unroll
        for (int q = 0; q < 4; ++q) {
          const int slot = i0 + wv * 32 + mi * 16 + grp * 4 + q;
          if (slot < m) {
            atomicAdd(&sAllG[slot], sA[q]);
            atomicAdd(&sPosG[slot], sP[q]);
          }
        }
      }
    }
  }
  // ---- completion-counter finalize (last block) ----
  __syncthreads();
  if (t == 0) {
    __threadfence();
    const unsigned v = atomicAdd(doneCnt, 1u);
    isLast = (v == gridDim.x - 1);
  }
  __syncthreads();
  if (!isLast) return;
  __threadfence();
  const int nvalid = (m >= 2) ? m : 0;
  float s = 0.f;
  for (int i = t; i < nvalid; i += 256) {
    const float sp = atomicAdd(&sPosG[i], 0.f);   // coherent read
    const float sa = atomicAdd(&sAllG[i], 0.f);
    s += -logf(sp / (sa + 1e-8f) + 1e-8f);
  }
  #pragma unroll
  for (int o = 32; o > 0; o >>= 1) s += __shfl_xor(s, o);
  if (lane == 0) red[wid] = s;
  __syncthreads();
  if (t == 0) {
    const float total = red[0] + red[1] + red[2] + red[3];
    const float proto = atomicAdd(protoLossAcc, 0.f) / (float)NB;
    float loss = proto;
    if (nvalid > 0) loss = 0.7f * proto + 0.3f * (total / (float)nvalid);
    out[0] = loss;
  }
}

extern "C" void kernel_launch(void* const* d_in, const int* in_sizes, int n_in,
                              void* d_out, int out_size, void* d_ws, size_t ws_size,
                              hipStream_t stream) {
  const float* z = (const float*)d_in[0];
  const float* attr = (const float*)d_in[1];
  unsigned short* znb = (unsigned short*)d_ws;            // NB*ND bf16 (8 MB)
  // ---- zeroed region ----
  float* sAllG = (float*)(znb + (size_t)NB * ND);         // NB
  float* sPosG = sAllG + NB;                              // NB
  float* protoLossAcc = sPosG + NB;                       // 1
  int* validCnt = (int*)(protoLossAcc + 1);               // 1
  unsigned* doneCnt = (unsigned*)(validCnt + 1);          // 1
  float* cntPart = (float*)(doneCnt + 1);                 // NSLOT*NPROTO
  float* protoPart = cntPart + NSLOT * NPROTO;            // NSLOT*NPROTO*ND (2 MB)
  float* zeroEnd = protoPart + (size_t)NSLOT * NPROTO * ND;
  // ---- non-zeroed ----
  int* code = (int*)zeroEnd;                              // NB
  int* validList = code + NB;                             // NB
  float* protos = (float*)(validList + NB);               // NPROTO*ND
  const size_t zeroBytes = (size_t)((char*)zeroEnd - (char*)sAllG);
  hipMemsetAsync(sAllG, 0, zeroBytes, stream);
  k_norm<<<dim3(NBLK), dim3(512), 0, stream>>>(z, attr, znb, protoPart, cntPart,
                                               code, validList, validCnt);
  k_protonorm<<<dim3(NPROTO), dim3(512), 0, stream>>>(protoPart, cntPart, protos);
  k_protoloss<<<dim3(256), dim3(256), 0, stream>>>(znb, protos, code, protoLossAcc);
  k_pairwise<<<dim3(512), dim3(256), 0, stream>>>(znb, code, validList, validCnt,
                                                  sAllG, sPosG, protoLossAcc, doneCnt,
                                                  (float*)d_out);
}

// Round 6
// 112.584 us; speedup vs baseline: 1.5629x; 1.5629x over previous
//
#include <hip/hip_runtime.h>
#include <math.h>

#define NB 8192
#define ND 512
#define NPROTO 16
#define NBLK 256                   // k_norm grid
#define TINV 14.285714285714286f   // 1/0.07
#define PW_BLOCKS 512
#define PL_BLOCKS 256

typedef short short8 __attribute__((ext_vector_type(8)));
typedef float float4v __attribute__((ext_vector_type(4)));

__device__ __forceinline__ unsigned short f2bf(float f) {
  unsigned u = __builtin_bit_cast(unsigned, f);
  unsigned r = (u + 0x7FFFu + ((u >> 16) & 1u)) >> 16;
  return (unsigned short)r;
}
__device__ __forceinline__ float bflo(unsigned u) {
  return __builtin_bit_cast(float, u << 16);
}
__device__ __forceinline__ float bfhi(unsigned u) {
  return __builtin_bit_cast(float, u & 0xFFFF0000u);
}

// ---- K1: wave-per-row normalize + bf16 store + non-atomic partial sums ----
__global__ __launch_bounds__(512) void k_norm(
    const float* __restrict__ z, const float* __restrict__ attr,
    unsigned short* __restrict__ znb, float* __restrict__ partialSum,
    int* __restrict__ code, float* __restrict__ protoLossAcc,
    unsigned* __restrict__ doneCnt)
{
  __shared__ float acc[NPROTO * ND];   // 32 KB
  const int t = threadIdx.x, lane = t & 63, wid = t >> 6;
  for (int i = t; i < NPROTO * ND; i += 512) acc[i] = 0.f;
  if (blockIdx.x == 0 && t == 0) { protoLossAcc[0] = 0.f; doneCnt[0] = 0u; }
  __syncthreads();
  #pragma unroll
  for (int rr = 0; rr < 4; ++rr) {
    const int r = blockIdx.x * 32 + wid * 4 + rr;
    const float* zr = z + (size_t)r * ND;
    float v[8];
    #pragma unroll
    for (int jj = 0; jj < 8; ++jj) v[jj] = zr[lane + jj * 64];
    float s = 0.f;
    #pragma unroll
    for (int jj = 0; jj < 8; ++jj) s += v[jj] * v[jj];
    #pragma unroll
    for (int o = 32; o > 0; o >>= 1) s += __shfl_xor(s, o);
    const float inv = 1.f / fmaxf(sqrtf(s), 1e-12f);
    const float* a = attr + (size_t)r * 4;
    const int c = (a[0] > 0.5f ? 8 : 0) | (a[1] > 0.5f ? 4 : 0) |
                  (a[2] > 0.5f ? 2 : 0) | (a[3] > 0.5f ? 1 : 0);
    float* accRow = acc + c * ND;
    #pragma unroll
    for (int jj = 0; jj < 8; ++jj) {
      const float zv = v[jj] * inv;
      atomicAdd(&accRow[lane + jj * 64], zv);        // LDS, consecutive banks
      znb[(size_t)r * ND + lane + jj * 64] = f2bf(zv);
    }
    if (lane == 0) code[r] = c;
  }
  __syncthreads();
  for (int i = t; i < NPROTO * ND; i += 512)        // full overwrite: no pre-zero
    partialSum[(size_t)blockIdx.x * (NPROTO * ND) + i] = acc[i];
}

// ---- K2: 16 blocks x 512 thr: reduce partials, count codes, normalize,
//          build validList (block 15), zero sAll/sPos ------------------------
__global__ __launch_bounds__(512) void k_protonorm(
    const float* __restrict__ partialSum, const int* __restrict__ code,
    float* __restrict__ protos, int* __restrict__ validList,
    int* __restrict__ validCnt, float* __restrict__ sAllG,
    float* __restrict__ sPosG)
{
  __shared__ float red[8];
  __shared__ int lcnt;
  const int t = threadIdx.x, lane = t & 63, wid = t >> 6;
  const int p = blockIdx.x;
  if (t == 0) lcnt = 0;
  __syncthreads();
  // reduce partial sums: thread t owns dim t, sums 256 block-partials
  float s = 0.f;
  #pragma unroll 8
  for (int b = 0; b < NBLK; ++b)
    s += partialSum[(size_t)b * (NPROTO * ND) + p * ND + t];
  // count rows with code==p (block 15 also compacts the valid list)
  float cl = 0.f;
  for (int r = t; r < NB; r += 512) {
    const int match = (code[r] == p) ? 1 : 0;
    cl += (float)match;
    if (p == NPROTO - 1 && match) {
      const int slot = atomicAdd(&lcnt, 1);
      validList[slot] = r;
    }
  }
  #pragma unroll
  for (int o = 32; o > 0; o >>= 1) cl += __shfl_xor(cl, o);
  if (lane == 0) red[wid] = cl;
  __syncthreads();
  const float cTot = red[0]+red[1]+red[2]+red[3]+red[4]+red[5]+red[6]+red[7];
  __syncthreads();
  const float mean = s / fmaxf(cTot, 1.f);
  float sq = mean * mean;
  #pragma unroll
  for (int o = 32; o > 0; o >>= 1) sq += __shfl_xor(sq, o);
  if (lane == 0) red[wid] = sq;
  __syncthreads();
  const float sum = red[0]+red[1]+red[2]+red[3]+red[4]+red[5]+red[6]+red[7];
  const float scale = (cTot > 0.f) ? 1.f / fmaxf(sqrtf(sum), 1e-12f) : 0.f;
  protos[p * ND + t] = mean * scale;
  // zero accumulators (16 blocks x 512 threads covers 8192)
  sAllG[p * 512 + t] = 0.f;
  sPosG[p * 512 + t] = 0.f;
  if (p == NPROTO - 1 && t == 0) validCnt[0] = lcnt;
}

// ---- K3: fused {pairwise MFMA GEMM | protoloss} + completion finalize -----
#define PLD (ND + 4)
#define SMEM_BYTES 33280
__global__ __launch_bounds__(256) void k_main(
    const unsigned short* __restrict__ znb, const float* __restrict__ protos,
    const int* __restrict__ code, const int* __restrict__ validList,
    const int* __restrict__ validCnt,
    float* __restrict__ sAllG, float* __restrict__ sPosG,
    float* __restrict__ protoLossAcc, unsigned* __restrict__ doneCnt,
    float* __restrict__ out)
{
  __shared__ __align__(16) char smem[SMEM_BYTES];
  __shared__ float red[8];
  __shared__ bool isLast;
  const int t = threadIdx.x, lane = t & 63, wid = t >> 6;
  const int bi = blockIdx.x;
  if (bi < PW_BLOCKS) {
    // ---------------- pairwise part (R4-proven GEMM loop) ----------------
    unsigned short* aT = (unsigned short*)smem;             // 64x64, 8 KB
    unsigned short* bT = aT + 64 * 64;                      // 128x64, 16 KB
    int* rowIdx = (int*)(bT + 128 * 64);                    // 64
    unsigned char* aoSh = (unsigned char*)(rowIdx + 64);    // 128
    const int ww = wid & 1, wv = wid >> 1;
    const int m = validCnt[0];
    const int nIT = (m + 63) >> 6;
    const int items = nIT * 64;
    const int grp = lane >> 4, cl = lane & 15;
    for (int wi = bi; wi < items; wi += PW_BLOCKS) {
      const int i0 = (wi >> 6) * 64;
      const int jb = (wi & 63) * 128;
      __syncthreads();
      if (t < 64) rowIdx[t] = (i0 + t < m) ? validList[i0 + t] : -1;
      if (t < 128) aoSh[t] = (code[jb + t] == NPROTO - 1) ? 1 : 0;
      float4v acc[2][4];
      #pragma unroll
      for (int mi = 0; mi < 2; ++mi)
        #pragma unroll
        for (int nj = 0; nj < 4; ++nj) acc[mi][nj] = (float4v)(0.f);
      for (int kc = 0; kc < 8; ++kc) {
        const int k0 = kc * 64;
        __syncthreads();
        {  // stage A: gathered via validList (64 rows x 8 chunks, 2/thread)
          const int ia = t >> 2;
          const int ri = rowIdx[ia];
          const int srow = (ri < 0) ? 0 : ri;
          #pragma unroll
          for (int h = 0; h < 2; ++h) {
            const int kq = (t & 3) + h * 4;
            const uint4 v = *(const uint4*)(znb + (size_t)srow * ND + k0 + kq * 8);
            *(uint4*)((char*)aT + ia * 128 + ((kq * 16) ^ ((ia & 7) << 4))) = v;
          }
        }
        #pragma unroll
        for (int h = 0; h < 4; ++h) {  // stage B: 128 rows x 8 chunks, 4/thread
          const int f = t + h * 256;
          const int j = f >> 3, kq = f & 7;
          const uint4 v = *(const uint4*)(znb + (size_t)(jb + j) * ND + k0 + kq * 8);
          *(uint4*)((char*)bT + j * 128 + ((kq * 16) ^ ((j & 7) << 4))) = v;
        }
        __syncthreads();
        #pragma unroll
        for (int ks = 0; ks < 2; ++ks) {
          const int kb = ks * 64 + grp * 16;
          short8 af[2], bf[4];
          #pragma unroll
          for (int mi = 0; mi < 2; ++mi) {
            const int rw = wv * 32 + mi * 16 + cl;
            af[mi] = *(const short8*)((char*)aT + rw * 128 + (kb ^ ((rw & 7) << 4)));
          }
          #pragma unroll
          for (int nj = 0; nj < 4; ++nj) {
            const int rw = ww * 64 + nj * 16 + cl;
            bf[nj] = *(const short8*)((char*)bT + rw * 128 + (kb ^ ((rw & 7) << 4)));
          }
          #pragma unroll
          for (int mi = 0; mi < 2; ++mi)
            #pragma unroll
            for (int nj = 0; nj < 4; ++nj)
              acc[mi][nj] = __builtin_amdgcn_mfma_f32_16x16x32_bf16(af[mi], bf[nj], acc[mi][nj], 0, 0, 0);
        }
      }
      // epilogue: exp, diag+pos masks, row sums, atomics
      #pragma unroll
      for (int mi = 0; mi < 2; ++mi) {
        float sA[4] = {0.f, 0.f, 0.f, 0.f}, sP[4] = {0.f, 0.f, 0.f, 0.f};
        int ri[4];
        #pragma unroll
        for (int q = 0; q < 4; ++q) ri[q] = rowIdx[wv * 32 + mi * 16 + grp * 4 + q];
        #pragma unroll
        for (int nj = 0; nj < 4; ++nj) {
          const int jl = ww * 64 + nj * 16 + cl;
          const int jg = jb + jl;
          const float ao = aoSh[jl] ? 1.f : 0.f;
          #pragma unroll
          for (int q = 0; q < 4; ++q) {
            float e = __expf(acc[mi][nj][q] * TINV);
            e = (jg == ri[q]) ? 0.f : e;
            sA[q] += e;
            sP[q] += e * ao;
          }
        }
        #pragma unroll
        for (int q = 0; q < 4; ++q) {
          #pragma unroll
          for (int o = 1; o < 16; o <<= 1) {
            sA[q] += __shfl_xor(sA[q], o);
            sP[q] += __shfl_xor(sP[q], o);
          }
        }
        if (cl == 0) {
          #pragma unroll
          for (int q = 0; q < 4; ++q) {
            const int slot = i0 + wv * 32 + mi * 16 + grp * 4 + q;
            if (slot < m) {
              atomicAdd(&sAllG[slot], sA[q]);
              atomicAdd(&sPosG[slot], sP[q]);
            }
          }
        }
      }
    }
  } else {
    // ---------------- protoloss part ----------------
    float* pl = (float*)smem;                               // 16 x PLD
    const int pb = bi - PW_BLOCKS;
    for (int i = t; i < NPROTO * ND; i += 256)
      pl[(i >> 9) * PLD + (i & 511)] = protos[i];
    __syncthreads();
    const int p = lane & 15, grp = lane >> 4;
    float lacc = 0.f;
    for (int r = pb * 4 + wid; r < NB; r += PL_BLOCKS * 4) {
      const uint4* zr = (const uint4*)(znb + (size_t)r * ND + grp * 128);
      const float* pbp = &pl[p * PLD + grp * 128];
      float s = 0.f;
      #pragma unroll
      for (int it = 0; it < 16; ++it) {
        const uint4 u = zr[it];
        const float4 p0 = *(const float4*)(pbp + it * 8);
        const float4 p1 = *(const float4*)(pbp + it * 8 + 4);
        s += bflo(u.x)*p0.x + bfhi(u.x)*p0.y + bflo(u.y)*p0.z + bfhi(u.y)*p0.w;
        s += bflo(u.z)*p1.x + bfhi(u.z)*p1.y + bflo(u.w)*p1.z + bfhi(u.w)*p1.w;
      }
      s += __shfl_xor(s, 16);
      s += __shfl_xor(s, 32);
      const float e = __expf(s * TINV);
      float alls = e;
      alls += __shfl_xor(alls, 1);
      alls += __shfl_xor(alls, 2);
      alls += __shfl_xor(alls, 4);
      alls += __shfl_xor(alls, 8);
      const int c = code[r];
      const float pos = __shfl(e, (lane & ~15) | c);
      if (lane == 0) lacc += -logf(pos / fmaxf(alls, 1e-8f) + 1e-8f);
    }
    if (lane == 0) atomicAdd(protoLossAcc, lacc);
  }
  // ---- completion-counter finalize (last block of all 768) ----
  __syncthreads();
  if (t == 0) {
    __threadfence();
    const unsigned v = atomicAdd(doneCnt, 1u);
    isLast = (v == gridDim.x - 1);
  }
  __syncthreads();
  if (!isLast) return;
  __threadfence();
  const int mv = validCnt[0];
  const int nvalid = (mv >= 2) ? mv : 0;
  float s = 0.f;
  for (int i = t; i < nvalid; i += 256) {
    const float sp = atomicAdd(&sPosG[i], 0.f);   // coherent read
    const float sa = atomicAdd(&sAllG[i], 0.f);
    s += -logf(sp / (sa + 1e-8f) + 1e-8f);
  }
  #pragma unroll
  for (int o = 32; o > 0; o >>= 1) s += __shfl_xor(s, o);
  if (lane == 0) red[wid] = s;
  __syncthreads();
  if (t == 0) {
    const float total = red[0] + red[1] + red[2] + red[3];
    const float proto = atomicAdd(protoLossAcc, 0.f) / (float)NB;
    float loss = proto;
    if (nvalid > 0) loss = 0.7f * proto + 0.3f * (total / (float)nvalid);
    out[0] = loss;
  }
}

extern "C" void kernel_launch(void* const* d_in, const int* in_sizes, int n_in,
                              void* d_out, int out_size, void* d_ws, size_t ws_size,
                              hipStream_t stream) {
  const float* z = (const float*)d_in[0];
  const float* attr = (const float*)d_in[1];
  unsigned short* znb = (unsigned short*)d_ws;            // NB*ND bf16 (8 MB)
  float* partialSum = (float*)(znb + (size_t)NB * ND);    // NBLK*NPROTO*ND (8 MB)
  float* sAllG = partialSum + (size_t)NBLK * NPROTO * ND; // NB
  float* sPosG = sAllG + NB;                              // NB
  float* protoLossAcc = sPosG + NB;                       // 1
  int* validCnt = (int*)(protoLossAcc + 1);               // 1
  unsigned* doneCnt = (unsigned*)(validCnt + 1);          // 1
  int* code = (int*)(doneCnt + 1);                        // NB
  int* validList = code + NB;                             // NB
  float* protos = (float*)(validList + NB);               // NPROTO*ND
  k_norm<<<dim3(NBLK), dim3(512), 0, stream>>>(z, attr, znb, partialSum, code,
                                               protoLossAcc, doneCnt);
  k_protonorm<<<dim3(NPROTO), dim3(512), 0, stream>>>(partialSum, code, protos,
                                                      validList, validCnt,
                                                      sAllG, sPosG);
  k_main<<<dim3(PW_BLOCKS + PL_BLOCKS), dim3(256), 0, stream>>>(
      znb, protos, code, validList, validCnt, sAllG, sPosG,
      protoLossAcc, doneCnt, (float*)d_out);
}

// Round 7
// 105.811 us; speedup vs baseline: 1.6629x; 1.0640x over previous
//
#include <hip/hip_runtime.h>
#include <math.h>

#define NB 8192
#define ND 512
#define NPROTO 16
#define NBLK 256                   // k_norm grid
#define TINV 14.285714285714286f   // 1/0.07
#define PW_BLOCKS 512
#define PL_BLOCKS 256

typedef short short8 __attribute__((ext_vector_type(8)));
typedef float float4v __attribute__((ext_vector_type(4)));

__device__ __forceinline__ unsigned short f2bf(float f) {
  unsigned u = __builtin_bit_cast(unsigned, f);
  unsigned r = (u + 0x7FFFu + ((u >> 16) & 1u)) >> 16;
  return (unsigned short)r;
}
__device__ __forceinline__ float bflo(unsigned u) {
  return __builtin_bit_cast(float, u << 16);
}
__device__ __forceinline__ float bfhi(unsigned u) {
  return __builtin_bit_cast(float, u & 0xFFFF0000u);
}

// ---- K1: wave-per-row normalize + bf16 store + non-atomic partial sums ----
__global__ __launch_bounds__(512) void k_norm(
    const float* __restrict__ z, const float* __restrict__ attr,
    unsigned short* __restrict__ znb, float* __restrict__ partialSum,
    int* __restrict__ code, float* __restrict__ protoLossAcc)
{
  __shared__ float acc[NPROTO * ND];   // 32 KB
  const int t = threadIdx.x, lane = t & 63, wid = t >> 6;
  for (int i = t; i < NPROTO * ND; i += 512) acc[i] = 0.f;
  if (blockIdx.x == 0 && t == 0) protoLossAcc[0] = 0.f;
  __syncthreads();
  #pragma unroll
  for (int rr = 0; rr < 4; ++rr) {
    const int r = blockIdx.x * 32 + wid * 4 + rr;
    const float* zr = z + (size_t)r * ND;
    float v[8];
    #pragma unroll
    for (int jj = 0; jj < 8; ++jj) v[jj] = zr[lane + jj * 64];
    float s = 0.f;
    #pragma unroll
    for (int jj = 0; jj < 8; ++jj) s += v[jj] * v[jj];
    #pragma unroll
    for (int o = 32; o > 0; o >>= 1) s += __shfl_xor(s, o);
    const float inv = 1.f / fmaxf(sqrtf(s), 1e-12f);
    const float* a = attr + (size_t)r * 4;
    const int c = (a[0] > 0.5f ? 8 : 0) | (a[1] > 0.5f ? 4 : 0) |
                  (a[2] > 0.5f ? 2 : 0) | (a[3] > 0.5f ? 1 : 0);
    float* accRow = acc + c * ND;
    #pragma unroll
    for (int jj = 0; jj < 8; ++jj) {
      const float zv = v[jj] * inv;
      atomicAdd(&accRow[lane + jj * 64], zv);        // LDS, consecutive banks
      znb[(size_t)r * ND + lane + jj * 64] = f2bf(zv);
    }
    if (lane == 0) code[r] = c;
  }
  __syncthreads();
  for (int i = t; i < NPROTO * ND; i += 512)        // full overwrite: no pre-zero
    partialSum[(size_t)blockIdx.x * (NPROTO * ND) + i] = acc[i];
}

// ---- K2: 16 blocks x 512 thr: reduce partials, count codes, normalize,
//          build validList (block 15), zero sAll/sPos ------------------------
__global__ __launch_bounds__(512) void k_protonorm(
    const float* __restrict__ partialSum, const int* __restrict__ code,
    float* __restrict__ protos, int* __restrict__ validList,
    int* __restrict__ validCnt, float* __restrict__ sAllG,
    float* __restrict__ sPosG)
{
  __shared__ float red[8];
  __shared__ int lcnt;
  const int t = threadIdx.x, lane = t & 63, wid = t >> 6;
  const int p = blockIdx.x;
  if (t == 0) lcnt = 0;
  __syncthreads();
  // reduce partial sums: thread t owns dim t, sums 256 block-partials
  float s = 0.f;
  #pragma unroll 8
  for (int b = 0; b < NBLK; ++b)
    s += partialSum[(size_t)b * (NPROTO * ND) + p * ND + t];
  // count rows with code==p (block 15 also compacts the valid list)
  float cl = 0.f;
  for (int r = t; r < NB; r += 512) {
    const int match = (code[r] == p) ? 1 : 0;
    cl += (float)match;
    if (p == NPROTO - 1 && match) {
      const int slot = atomicAdd(&lcnt, 1);
      validList[slot] = r;
    }
  }
  #pragma unroll
  for (int o = 32; o > 0; o >>= 1) cl += __shfl_xor(cl, o);
  if (lane == 0) red[wid] = cl;
  __syncthreads();
  const float cTot = red[0]+red[1]+red[2]+red[3]+red[4]+red[5]+red[6]+red[7];
  __syncthreads();
  const float mean = s / fmaxf(cTot, 1.f);
  float sq = mean * mean;
  #pragma unroll
  for (int o = 32; o > 0; o >>= 1) sq += __shfl_xor(sq, o);
  if (lane == 0) red[wid] = sq;
  __syncthreads();
  const float sum = red[0]+red[1]+red[2]+red[3]+red[4]+red[5]+red[6]+red[7];
  const float scale = (cTot > 0.f) ? 1.f / fmaxf(sqrtf(sum), 1e-12f) : 0.f;
  protos[p * ND + t] = mean * scale;
  // zero accumulators (16 blocks x 512 threads covers 8192)
  sAllG[p * 512 + t] = 0.f;
  sPosG[p * 512 + t] = 0.f;
  if (p == NPROTO - 1 && t == 0) validCnt[0] = lcnt;
}

// ---- K3: fused {pairwise MFMA GEMM | protoloss}, no in-kernel finalize ----
#define PLD (ND + 4)
#define SMEM_BYTES 33280
__global__ __launch_bounds__(256) void k_main(
    const unsigned short* __restrict__ znb, const float* __restrict__ protos,
    const int* __restrict__ code, const int* __restrict__ validList,
    const int* __restrict__ validCnt,
    float* __restrict__ sAllG, float* __restrict__ sPosG,
    float* __restrict__ protoLossAcc)
{
  __shared__ __align__(16) char smem[SMEM_BYTES];
  const int t = threadIdx.x, lane = t & 63, wid = t >> 6;
  const int bi = blockIdx.x;
  if (bi < PW_BLOCKS) {
    // ---------------- pairwise part (R4-proven GEMM loop) ----------------
    unsigned short* aT = (unsigned short*)smem;             // 64x64, 8 KB
    unsigned short* bT = aT + 64 * 64;                      // 128x64, 16 KB
    int* rowIdx = (int*)(bT + 128 * 64);                    // 64
    unsigned char* aoSh = (unsigned char*)(rowIdx + 64);    // 128
    const int ww = wid & 1, wv = wid >> 1;
    const int m = validCnt[0];
    const int nIT = (m + 63) >> 6;
    const int items = nIT * 64;
    const int grp = lane >> 4, cl = lane & 15;
    for (int wi = bi; wi < items; wi += PW_BLOCKS) {
      const int i0 = (wi >> 6) * 64;
      const int jb = (wi & 63) * 128;
      __syncthreads();
      if (t < 64) rowIdx[t] = (i0 + t < m) ? validList[i0 + t] : -1;
      if (t < 128) aoSh[t] = (code[jb + t] == NPROTO - 1) ? 1 : 0;
      float4v acc[2][4];
      #pragma unroll
      for (int mi = 0; mi < 2; ++mi)
        #pragma unroll
        for (int nj = 0; nj < 4; ++nj) acc[mi][nj] = (float4v)(0.f);
      for (int kc = 0; kc < 8; ++kc) {
        const int k0 = kc * 64;
        __syncthreads();
        {  // stage A: gathered via validList (64 rows x 8 chunks, 2/thread)
          const int ia = t >> 2;
          const int ri = rowIdx[ia];
          const int srow = (ri < 0) ? 0 : ri;
          #pragma unroll
          for (int h = 0; h < 2; ++h) {
            const int kq = (t & 3) + h * 4;
            const uint4 v = *(const uint4*)(znb + (size_t)srow * ND + k0 + kq * 8);
            *(uint4*)((char*)aT + ia * 128 + ((kq * 16) ^ ((ia & 7) << 4))) = v;
          }
        }
        #pragma unroll
        for (int h = 0; h < 4; ++h) {  // stage B: 128 rows x 8 chunks, 4/thread
          const int f = t + h * 256;
          const int j = f >> 3, kq = f & 7;
          const uint4 v = *(const uint4*)(znb + (size_t)(jb + j) * ND + k0 + kq * 8);
          *(uint4*)((char*)bT + j * 128 + ((kq * 16) ^ ((j & 7) << 4))) = v;
        }
        __syncthreads();
        #pragma unroll
        for (int ks = 0; ks < 2; ++ks) {
          const int kb = ks * 64 + grp * 16;
          short8 af[2], bf[4];
          #pragma unroll
          for (int mi = 0; mi < 2; ++mi) {
            const int rw = wv * 32 + mi * 16 + cl;
            af[mi] = *(const short8*)((char*)aT + rw * 128 + (kb ^ ((rw & 7) << 4)));
          }
          #pragma unroll
          for (int nj = 0; nj < 4; ++nj) {
            const int rw = ww * 64 + nj * 16 + cl;
            bf[nj] = *(const short8*)((char*)bT + rw * 128 + (kb ^ ((rw & 7) << 4)));
          }
          #pragma unroll
          for (int mi = 0; mi < 2; ++mi)
            #pragma unroll
            for (int nj = 0; nj < 4; ++nj)
              acc[mi][nj] = __builtin_amdgcn_mfma_f32_16x16x32_bf16(af[mi], bf[nj], acc[mi][nj], 0, 0, 0);
        }
      }
      // epilogue: exp, diag+pos masks, row sums, atomics
      #pragma unroll
      for (int mi = 0; mi < 2; ++mi) {
        float sA[4] = {0.f, 0.f, 0.f, 0.f}, sP[4] = {0.f, 0.f, 0.f, 0.f};
        int ri[4];
        #pragma unroll
        for (int q = 0; q < 4; ++q) ri[q] = rowIdx[wv * 32 + mi * 16 + grp * 4 + q];
        #pragma unroll
        for (int nj = 0; nj < 4; ++nj) {
          const int jl = ww * 64 + nj * 16 + cl;
          const int jg = jb + jl;
          const float ao = aoSh[jl] ? 1.f : 0.f;
          #pragma unroll
          for (int q = 0; q < 4; ++q) {
            float e = __expf(acc[mi][nj][q] * TINV);
            e = (jg == ri[q]) ? 0.f : e;
            sA[q] += e;
            sP[q] += e * ao;
          }
        }
        #pragma unroll
        for (int q = 0; q < 4; ++q) {
          #pragma unroll
          for (int o = 1; o < 16; o <<= 1) {
            sA[q] += __shfl_xor(sA[q], o);
            sP[q] += __shfl_xor(sP[q], o);
          }
        }
        if (cl == 0) {
          #pragma unroll
          for (int q = 0; q < 4; ++q) {
            const int slot = i0 + wv * 32 + mi * 16 + grp * 4 + q;
            if (slot < m) {
              atomicAdd(&sAllG[slot], sA[q]);
              atomicAdd(&sPosG[slot], sP[q]);
            }
          }
        }
      }
    }
  } else {
    // ---------------- protoloss part ----------------
    float* pl = (float*)smem;                               // 16 x PLD
    const int pb = bi - PW_BLOCKS;
    for (int i = t; i < NPROTO * ND; i += 256)
      pl[(i >> 9) * PLD + (i & 511)] = protos[i];
    __syncthreads();
    const int p = lane & 15, grp = lane >> 4;
    float lacc = 0.f;
    for (int r = pb * 4 + wid; r < NB; r += PL_BLOCKS * 4) {
      const uint4* zr = (const uint4*)(znb + (size_t)r * ND + grp * 128);
      const float* pbp = &pl[p * PLD + grp * 128];
      float s = 0.f;
      #pragma unroll
      for (int it = 0; it < 16; ++it) {
        const uint4 u = zr[it];
        const float4 p0 = *(const float4*)(pbp + it * 8);
        const float4 p1 = *(const float4*)(pbp + it * 8 + 4);
        s += bflo(u.x)*p0.x + bfhi(u.x)*p0.y + bflo(u.y)*p0.z + bfhi(u.y)*p0.w;
        s += bflo(u.z)*p1.x + bfhi(u.z)*p1.y + bflo(u.w)*p1.z + bfhi(u.w)*p1.w;
      }
      s += __shfl_xor(s, 16);
      s += __shfl_xor(s, 32);
      const float e = __expf(s * TINV);
      float alls = e;
      alls += __shfl_xor(alls, 1);
      alls += __shfl_xor(alls, 2);
      alls += __shfl_xor(alls, 4);
      alls += __shfl_xor(alls, 8);
      const int c = code[r];
      const float pos = __shfl(e, (lane & ~15) | c);
      if (lane == 0) lacc += -logf(pos / fmaxf(alls, 1e-8f) + 1e-8f);
    }
    if (lane == 0) atomicAdd(protoLossAcc, lacc);
  }
}

// ---- K4: finalize (separate dispatch; kernel boundary = coherence) --------
__global__ __launch_bounds__(512) void k_final(
    const float* __restrict__ sAllG, const float* __restrict__ sPosG,
    const float* __restrict__ protoLossAcc, const int* __restrict__ validCnt,
    float* __restrict__ out)
{
  __shared__ float red[8];
  const int t = threadIdx.x, lane = t & 63, wid = t >> 6;
  const int m = validCnt[0];
  const int nvalid = (m >= 2) ? m : 0;
  float s = 0.f;
  for (int i = t; i < nvalid; i += 512)
    s += -logf(sPosG[i] / (sAllG[i] + 1e-8f) + 1e-8f);
  #pragma unroll
  for (int o = 32; o > 0; o >>= 1) s += __shfl_xor(s, o);
  if (lane == 0) red[wid] = s;
  __syncthreads();
  if (t == 0) {
    const float total = red[0]+red[1]+red[2]+red[3]+red[4]+red[5]+red[6]+red[7];
    const float proto = protoLossAcc[0] / (float)NB;
    float loss = proto;
    if (nvalid > 0) loss = 0.7f * proto + 0.3f * (total / (float)nvalid);
    out[0] = loss;
  }
}

extern "C" void kernel_launch(void* const* d_in, const int* in_sizes, int n_in,
                              void* d_out, int out_size, void* d_ws, size_t ws_size,
                              hipStream_t stream) {
  const float* z = (const float*)d_in[0];
  const float* attr = (const float*)d_in[1];
  unsigned short* znb = (unsigned short*)d_ws;            // NB*ND bf16 (8 MB)
  float* partialSum = (float*)(znb + (size_t)NB * ND);    // NBLK*NPROTO*ND (8 MB)
  float* sAllG = partialSum + (size_t)NBLK * NPROTO * ND; // NB
  float* sPosG = sAllG + NB;                              // NB
  float* protoLossAcc = sPosG + NB;                       // 1
  int* validCnt = (int*)(protoLossAcc + 1);               // 1
  int* code = validCnt + 1;                               // NB
  int* validList = code + NB;                             // NB
  float* protos = (float*)(validList + NB);               // NPROTO*ND
  k_norm<<<dim3(NBLK), dim3(512), 0, stream>>>(z, attr, znb, partialSum, code,
                                               protoLossAcc);
  k_protonorm<<<dim3(NPROTO), dim3(512), 0, stream>>>(partialSum, code, protos,
                                                      validList, validCnt,
                                                      sAllG, sPosG);
  k_main<<<dim3(PW_BLOCKS + PL_BLOCKS), dim3(256), 0, stream>>>(
      znb, protos, code, validList, validCnt, sAllG, sPosG, protoLossAcc);
  k_final<<<dim3(1), dim3(512), 0, stream>>>(sAllG, sPosG, protoLossAcc, validCnt,
                                             (float*)d_out);
}

// Round 8
// 93.998 us; speedup vs baseline: 1.8719x; 1.1257x over previous
//
#include <hip/hip_runtime.h>
#include <math.h>

#define NB 8192
#define ND 512
#define NPROTO 16
#define NBLK 256                   // k_norm grid
#define TINV 14.285714285714286f   // 1/0.07
#define PW_BLOCKS 512
#define PL_BLOCKS 256

typedef short short8 __attribute__((ext_vector_type(8)));
typedef float float4v __attribute__((ext_vector_type(4)));

__device__ __forceinline__ unsigned short f2bf(float f) {
  unsigned u = __builtin_bit_cast(unsigned, f);
  unsigned r = (u + 0x7FFFu + ((u >> 16) & 1u)) >> 16;
  return (unsigned short)r;
}
__device__ __forceinline__ float bflo(unsigned u) {
  return __builtin_bit_cast(float, u << 16);
}
__device__ __forceinline__ float bfhi(unsigned u) {
  return __builtin_bit_cast(float, u & 0xFFFF0000u);
}

// ---- K1: wave-per-row normalize + bf16 store + non-atomic partial sums ----
__global__ __launch_bounds__(512) void k_norm(
    const float* __restrict__ z, const float* __restrict__ attr,
    unsigned short* __restrict__ znb, float* __restrict__ partialSum,
    int* __restrict__ code)
{
  __shared__ float acc[NPROTO * ND];   // 32 KB
  const int t = threadIdx.x, lane = t & 63, wid = t >> 6;
  for (int i = t; i < NPROTO * ND; i += 512) acc[i] = 0.f;
  __syncthreads();
  #pragma unroll
  for (int rr = 0; rr < 4; ++rr) {
    const int r = blockIdx.x * 32 + wid * 4 + rr;
    const float* zr = z + (size_t)r * ND;
    float v[8];
    #pragma unroll
    for (int jj = 0; jj < 8; ++jj) v[jj] = zr[lane + jj * 64];
    float s = 0.f;
    #pragma unroll
    for (int jj = 0; jj < 8; ++jj) s += v[jj] * v[jj];
    #pragma unroll
    for (int o = 32; o > 0; o >>= 1) s += __shfl_xor(s, o);
    const float inv = 1.f / fmaxf(sqrtf(s), 1e-12f);
    const float* a = attr + (size_t)r * 4;
    const int c = (a[0] > 0.5f ? 8 : 0) | (a[1] > 0.5f ? 4 : 0) |
                  (a[2] > 0.5f ? 2 : 0) | (a[3] > 0.5f ? 1 : 0);
    float* accRow = acc + c * ND;
    #pragma unroll
    for (int jj = 0; jj < 8; ++jj) {
      const float zv = v[jj] * inv;
      atomicAdd(&accRow[lane + jj * 64], zv);        // LDS, consecutive banks
      znb[(size_t)r * ND + lane + jj * 64] = f2bf(zv);
    }
    if (lane == 0) code[r] = c;
  }
  __syncthreads();
  for (int i = t; i < NPROTO * ND; i += 512)        // full overwrite: no pre-zero
    partialSum[(size_t)blockIdx.x * (NPROTO * ND) + i] = acc[i];
}

// ---- K2: 16 blocks x 512 thr: reduce partials, count codes, normalize,
//          build validList (block 15) ---------------------------------------
__global__ __launch_bounds__(512) void k_protonorm(
    const float* __restrict__ partialSum, const int* __restrict__ code,
    float* __restrict__ protos, int* __restrict__ validList,
    int* __restrict__ validCnt)
{
  __shared__ float red[8];
  __shared__ int lcnt;
  const int t = threadIdx.x, lane = t & 63, wid = t >> 6;
  const int p = blockIdx.x;
  if (t == 0) lcnt = 0;
  __syncthreads();
  // reduce partial sums: thread t owns dim t, sums 256 block-partials
  float s = 0.f;
  #pragma unroll 8
  for (int b = 0; b < NBLK; ++b)
    s += partialSum[(size_t)b * (NPROTO * ND) + p * ND + t];
  // count rows with code==p (block 15 also compacts the valid list)
  float cl = 0.f;
  for (int r = t; r < NB; r += 512) {
    const int match = (code[r] == p) ? 1 : 0;
    cl += (float)match;
    if (p == NPROTO - 1 && match) {
      const int slot = atomicAdd(&lcnt, 1);
      validList[slot] = r;
    }
  }
  #pragma unroll
  for (int o = 32; o > 0; o >>= 1) cl += __shfl_xor(cl, o);
  if (lane == 0) red[wid] = cl;
  __syncthreads();
  const float cTot = red[0]+red[1]+red[2]+red[3]+red[4]+red[5]+red[6]+red[7];
  __syncthreads();
  const float mean = s / fmaxf(cTot, 1.f);
  float sq = mean * mean;
  #pragma unroll
  for (int o = 32; o > 0; o >>= 1) sq += __shfl_xor(sq, o);
  if (lane == 0) red[wid] = sq;
  __syncthreads();
  const float sum = red[0]+red[1]+red[2]+red[3]+red[4]+red[5]+red[6]+red[7];
  const float scale = (cTot > 0.f) ? 1.f / fmaxf(sqrtf(sum), 1e-12f) : 0.f;
  protos[p * ND + t] = mean * scale;
  if (p == NPROTO - 1 && t == 0) validCnt[0] = lcnt;
}

// ---- K3: fused {pairwise MFMA GEMM | protoloss}, NO global atomics --------
#define PLD (ND + 4)
#define SMEM_BYTES 33280
__global__ __launch_bounds__(256) void k_main(
    const unsigned short* __restrict__ znb, const float* __restrict__ protos,
    const int* __restrict__ code, const int* __restrict__ validList,
    const int* __restrict__ validCnt,
    float* __restrict__ partialAll, float* __restrict__ partialPos,
    float* __restrict__ plPart)
{
  __shared__ __align__(16) char smem[SMEM_BYTES];
  __shared__ float red3[4];
  const int t = threadIdx.x, lane = t & 63, wid = t >> 6;
  const int bi = blockIdx.x;
  if (bi < PW_BLOCKS) {
    // ---------------- pairwise part ----------------
    unsigned short* aT = (unsigned short*)smem;             // 64x64, 8 KB
    unsigned short* bT = aT + 64 * 64;                      // 128x64, 16 KB
    int* rowIdx = (int*)(bT + 128 * 64);                    // 64
    unsigned char* aoSh = (unsigned char*)(rowIdx + 64);    // 128
    const int ww = wid & 1, wv = wid >> 1;
    const int m = validCnt[0];
    const int nIT = (m + 63) >> 6;
    const int items = nIT * 64;
    const int grp = lane >> 4, cl = lane & 15;
    for (int wi = bi; wi < items; wi += PW_BLOCKS) {
      const int i0 = (wi >> 6) * 64;
      const int jt = wi & 63;
      const int jb = jt * 128;
      __syncthreads();
      if (t < 64) rowIdx[t] = (i0 + t < m) ? validList[i0 + t] : -1;
      if (t < 128) aoSh[t] = (code[jb + t] == NPROTO - 1) ? 1 : 0;
      float4v acc[2][4];
      #pragma unroll
      for (int mi = 0; mi < 2; ++mi)
        #pragma unroll
        for (int nj = 0; nj < 4; ++nj) acc[mi][nj] = (float4v)(0.f);
      for (int kc = 0; kc < 8; ++kc) {
        const int k0 = kc * 64;
        __syncthreads();
        {  // stage A: gathered via validList (64 rows x 8 chunks, 2/thread)
          const int ia = t >> 2;
          const int ri = rowIdx[ia];
          const int srow = (ri < 0) ? 0 : ri;
          #pragma unroll
          for (int h = 0; h < 2; ++h) {
            const int kq = (t & 3) + h * 4;
            const uint4 v = *(const uint4*)(znb + (size_t)srow * ND + k0 + kq * 8);
            *(uint4*)((char*)aT + ia * 128 + ((kq * 16) ^ ((ia & 7) << 4))) = v;
          }
        }
        #pragma unroll
        for (int h = 0; h < 4; ++h) {  // stage B: 128 rows x 8 chunks, 4/thread
          const int f = t + h * 256;
          const int j = f >> 3, kq = f & 7;
          const uint4 v = *(const uint4*)(znb + (size_t)(jb + j) * ND + k0 + kq * 8);
          *(uint4*)((char*)bT + j * 128 + ((kq * 16) ^ ((j & 7) << 4))) = v;
        }
        __syncthreads();
        #pragma unroll
        for (int ks = 0; ks < 2; ++ks) {
          const int kb = ks * 64 + grp * 16;
          short8 af[2], bf[4];
          #pragma unroll
          for (int mi = 0; mi < 2; ++mi) {
            const int rw = wv * 32 + mi * 16 + cl;
            af[mi] = *(const short8*)((char*)aT + rw * 128 + (kb ^ ((rw & 7) << 4)));
          }
          #pragma unroll
          for (int nj = 0; nj < 4; ++nj) {
            const int rw = ww * 64 + nj * 16 + cl;
            bf[nj] = *(const short8*)((char*)bT + rw * 128 + (kb ^ ((rw & 7) << 4)));
          }
          #pragma unroll
          for (int mi = 0; mi < 2; ++mi)
            #pragma unroll
            for (int nj = 0; nj < 4; ++nj)
              acc[mi][nj] = __builtin_amdgcn_mfma_f32_16x16x32_bf16(af[mi], bf[nj], acc[mi][nj], 0, 0, 0);
        }
      }
      // epilogue: exp, diag+pos masks, row sums, DIRECT partial writes
      #pragma unroll
      for (int mi = 0; mi < 2; ++mi) {
        float sA[4] = {0.f, 0.f, 0.f, 0.f}, sP[4] = {0.f, 0.f, 0.f, 0.f};
        int ri[4];
        #pragma unroll
        for (int q = 0; q < 4; ++q) ri[q] = rowIdx[wv * 32 + mi * 16 + grp * 4 + q];
        #pragma unroll
        for (int nj = 0; nj < 4; ++nj) {
          const int jl = ww * 64 + nj * 16 + cl;
          const int jg = jb + jl;
          const float ao = aoSh[jl] ? 1.f : 0.f;
          #pragma unroll
          for (int q = 0; q < 4; ++q) {
            float e = __expf(acc[mi][nj][q] * TINV);
            e = (jg == ri[q]) ? 0.f : e;
            sA[q] += e;
            sP[q] += e * ao;
          }
        }
        #pragma unroll
        for (int q = 0; q < 4; ++q) {
          #pragma unroll
          for (int o = 1; o < 16; o <<= 1) {
            sA[q] += __shfl_xor(sA[q], o);
            sP[q] += __shfl_xor(sP[q], o);
          }
        }
        if (cl == 0) {
          #pragma unroll
          for (int q = 0; q < 4; ++q) {
            const int slot = i0 + wv * 32 + mi * 16 + grp * 4 + q;
            if (slot < m) {
              // unique producer per (slot, jt*2+ww): plain store, no atomic
              partialAll[(size_t)slot * 128 + jt * 2 + ww] = sA[q];
              partialPos[(size_t)slot * 128 + jt * 2 + ww] = sP[q];
            }
          }
        }
      }
    }
  } else {
    // ---------------- protoloss part ----------------
    float* pl = (float*)smem;                               // 16 x PLD
    const int pb = bi - PW_BLOCKS;
    for (int i = t; i < NPROTO * ND; i += 256)
      pl[(i >> 9) * PLD + (i & 511)] = protos[i];
    __syncthreads();
    const int p = lane & 15, grp = lane >> 4;
    float lacc = 0.f;
    for (int r = pb * 4 + wid; r < NB; r += PL_BLOCKS * 4) {
      const uint4* zr = (const uint4*)(znb + (size_t)r * ND + grp * 128);
      const float* pbp = &pl[p * PLD + grp * 128];
      float s = 0.f;
      #pragma unroll
      for (int it = 0; it < 16; ++it) {
        const uint4 u = zr[it];
        const float4 p0 = *(const float4*)(pbp + it * 8);
        const float4 p1 = *(const float4*)(pbp + it * 8 + 4);
        s += bflo(u.x)*p0.x + bfhi(u.x)*p0.y + bflo(u.y)*p0.z + bfhi(u.y)*p0.w;
        s += bflo(u.z)*p1.x + bfhi(u.z)*p1.y + bflo(u.w)*p1.z + bfhi(u.w)*p1.w;
      }
      s += __shfl_xor(s, 16);
      s += __shfl_xor(s, 32);
      const float e = __expf(s * TINV);
      float alls = e;
      alls += __shfl_xor(alls, 1);
      alls += __shfl_xor(alls, 2);
      alls += __shfl_xor(alls, 4);
      alls += __shfl_xor(alls, 8);
      const int c = code[r];
      const float pos = __shfl(e, (lane & ~15) | c);
      if (lane == 0) lacc += -logf(pos / fmaxf(alls, 1e-8f) + 1e-8f);
    }
    if (lane == 0) red3[wid] = lacc;
    __syncthreads();
    if (t == 0) plPart[pb] = red3[0] + red3[1] + red3[2] + red3[3];
  }
}

// ---- K4: finalize (separate dispatch; kernel boundary = coherence) --------
__global__ __launch_bounds__(512) void k_final(
    const float* __restrict__ partialAll, const float* __restrict__ partialPos,
    const float* __restrict__ plPart, const int* __restrict__ validCnt,
    float* __restrict__ out)
{
  __shared__ float red[8];
  __shared__ float red2[8];
  const int t = threadIdx.x, lane = t & 63, wid = t >> 6;
  const int m = validCnt[0];
  const int nvalid = (m >= 2) ? m : 0;
  float s = 0.f;
  for (int slot = t; slot < nvalid; slot += 512) {
    const float4* pa = (const float4*)(partialAll + (size_t)slot * 128);
    const float4* pp = (const float4*)(partialPos + (size_t)slot * 128);
    float sa = 0.f, sp = 0.f;
    #pragma unroll
    for (int i = 0; i < 32; ++i) {
      const float4 a = pa[i];
      sa += a.x + a.y + a.z + a.w;
      const float4 b = pp[i];
      sp += b.x + b.y + b.z + b.w;
    }
    s += -logf(sp / (sa + 1e-8f) + 1e-8f);
  }
  float pls = (t < PL_BLOCKS) ? plPart[t] : 0.f;
  #pragma unroll
  for (int o = 32; o > 0; o >>= 1) {
    s += __shfl_xor(s, o);
    pls += __shfl_xor(pls, o);
  }
  if (lane == 0) { red[wid] = s; red2[wid] = pls; }
  __syncthreads();
  if (t == 0) {
    const float total = red[0]+red[1]+red[2]+red[3]+red[4]+red[5]+red[6]+red[7];
    const float plTot = red2[0]+red2[1]+red2[2]+red2[3]+red2[4]+red2[5]+red2[6]+red2[7];
    const float proto = plTot / (float)NB;
    float loss = proto;
    if (nvalid > 0) loss = 0.7f * proto + 0.3f * (total / (float)nvalid);
    out[0] = loss;
  }
}

extern "C" void kernel_launch(void* const* d_in, const int* in_sizes, int n_in,
                              void* d_out, int out_size, void* d_ws, size_t ws_size,
                              hipStream_t stream) {
  const float* z = (const float*)d_in[0];
  const float* attr = (const float*)d_in[1];
  unsigned short* znb = (unsigned short*)d_ws;            // NB*ND bf16 (8 MB)
  float* partialSum = (float*)(znb + (size_t)NB * ND);    // NBLK*NPROTO*ND (8 MB)
  // overlay: partialSum is dead after k_protonorm; k_main reuses it
  float* partialAll = partialSum;                         // NB*128 (4 MB)
  float* partialPos = partialSum + (size_t)NB * 128;      // NB*128 (4 MB)
  int* validCnt = (int*)(partialSum + (size_t)NBLK * NPROTO * ND);  // 1
  int* code = validCnt + 1;                               // NB
  int* validList = code + NB;                             // NB
  float* protos = (float*)(validList + NB);               // NPROTO*ND
  float* plPart = protos + NPROTO * ND;                   // PL_BLOCKS
  k_norm<<<dim3(NBLK), dim3(512), 0, stream>>>(z, attr, znb, partialSum, code);
  k_protonorm<<<dim3(NPROTO), dim3(512), 0, stream>>>(partialSum, code, protos,
                                                      validList, validCnt);
  k_main<<<dim3(PW_BLOCKS + PL_BLOCKS), dim3(256), 0, stream>>>(
      znb, protos, code, validList, validCnt, partialAll, partialPos, plPart);
  k_final<<<dim3(1), dim3(512), 0, stream>>>(partialAll, partialPos, plPart,
                                             validCnt, (float*)d_out);
}

// Round 9
// 88.554 us; speedup vs baseline: 1.9870x; 1.0615x over previous
//
#include <hip/hip_runtime.h>
#include <math.h>

#define NB 8192
#define ND 512
#define NPROTO 16
#define NBLK 256                   // k_norm grid (must be 1<<8)
#define TINV 14.285714285714286f   // 1/0.07
#define PW_BLOCKS 512
#define PL_BLOCKS 256

typedef short short8 __attribute__((ext_vector_type(8)));
typedef float float4v __attribute__((ext_vector_type(4)));

__device__ __forceinline__ unsigned short f2bf(float f) {
  unsigned u = __builtin_bit_cast(unsigned, f);
  unsigned r = (u + 0x7FFFu + ((u >> 16) & 1u)) >> 16;
  return (unsigned short)r;
}
__device__ __forceinline__ float bflo(unsigned u) {
  return __builtin_bit_cast(float, u << 16);
}
__device__ __forceinline__ float bfhi(unsigned u) {
  return __builtin_bit_cast(float, u & 0xFFFF0000u);
}

// ---- K1: wave-per-row normalize + bf16 store + non-atomic partial sums ----
// partialSum layout: [p][block][d]  (coalesced write here, contiguous read in K2)
__global__ __launch_bounds__(512) void k_norm(
    const float* __restrict__ z, const float* __restrict__ attr,
    unsigned short* __restrict__ znb, float* __restrict__ partialSum,
    int* __restrict__ code)
{
  __shared__ float acc[NPROTO * ND];   // 32 KB
  const int t = threadIdx.x, lane = t & 63, wid = t >> 6;
  for (int i = t; i < NPROTO * ND; i += 512) acc[i] = 0.f;
  __syncthreads();
  #pragma unroll
  for (int rr = 0; rr < 4; ++rr) {
    const int r = blockIdx.x * 32 + wid * 4 + rr;
    const float* zr = z + (size_t)r * ND;
    float v[8];
    #pragma unroll
    for (int jj = 0; jj < 8; ++jj) v[jj] = zr[lane + jj * 64];
    float s = 0.f;
    #pragma unroll
    for (int jj = 0; jj < 8; ++jj) s += v[jj] * v[jj];
    #pragma unroll
    for (int o = 32; o > 0; o >>= 1) s += __shfl_xor(s, o);
    const float inv = 1.f / fmaxf(sqrtf(s), 1e-12f);
    const float* a = attr + (size_t)r * 4;
    const int c = (a[0] > 0.5f ? 8 : 0) | (a[1] > 0.5f ? 4 : 0) |
                  (a[2] > 0.5f ? 2 : 0) | (a[3] > 0.5f ? 1 : 0);
    float* accRow = acc + c * ND;
    #pragma unroll
    for (int jj = 0; jj < 8; ++jj) {
      const float zv = v[jj] * inv;
      atomicAdd(&accRow[lane + jj * 64], zv);        // LDS, consecutive banks
      znb[(size_t)r * ND + lane + jj * 64] = f2bf(zv);
    }
    if (lane == 0) code[r] = c;
  }
  __syncthreads();
  for (int i = t; i < NPROTO * ND; i += 512) {      // full overwrite: no pre-zero
    const int p = i >> 9, d = i & 511;
    partialSum[(size_t)((p << 8) | blockIdx.x) * ND + d] = acc[i];
  }
}

// ---- K2: 16 blocks x 512 thr: reduce partials (contiguous), count codes,
//          normalize, build validList (block 15) -----------------------------
__global__ __launch_bounds__(512) void k_protonorm(
    const float* __restrict__ partialSum, const int* __restrict__ code,
    float* __restrict__ protos, int* __restrict__ validList,
    int* __restrict__ validCnt)
{
  __shared__ float red[8];
  __shared__ int lcnt;
  const int t = threadIdx.x, lane = t & 63, wid = t >> 6;
  const int p = blockIdx.x;
  if (t == 0) lcnt = 0;
  __syncthreads();
  // reduce partial sums: thread t owns dim t; block p reads contiguous 512 KB
  const float* base = partialSum + (size_t)(p << 8) * ND;
  float s = 0.f;
  #pragma unroll 8
  for (int b = 0; b < NBLK; ++b)
    s += base[b * ND + t];
  // count rows with code==p (block 15 also compacts the valid list)
  float cl = 0.f;
  for (int r = t; r < NB; r += 512) {
    const int match = (code[r] == p) ? 1 : 0;
    cl += (float)match;
    if (p == NPROTO - 1 && match) {
      const int slot = atomicAdd(&lcnt, 1);
      validList[slot] = r;
    }
  }
  #pragma unroll
  for (int o = 32; o > 0; o >>= 1) cl += __shfl_xor(cl, o);
  if (lane == 0) red[wid] = cl;
  __syncthreads();
  const float cTot = red[0]+red[1]+red[2]+red[3]+red[4]+red[5]+red[6]+red[7];
  __syncthreads();
  const float mean = s / fmaxf(cTot, 1.f);
  float sq = mean * mean;
  #pragma unroll
  for (int o = 32; o > 0; o >>= 1) sq += __shfl_xor(sq, o);
  if (lane == 0) red[wid] = sq;
  __syncthreads();
  const float sum = red[0]+red[1]+red[2]+red[3]+red[4]+red[5]+red[6]+red[7];
  const float scale = (cTot > 0.f) ? 1.f / fmaxf(sqrtf(sum), 1e-12f) : 0.f;
  protos[p * ND + t] = mean * scale;
  if (p == NPROTO - 1 && t == 0) validCnt[0] = lcnt;
}

// ---- K3: fused {pairwise MFMA GEMM | protoloss}, NO global atomics --------
// partialAll/partialPos layout: [jt2][slot], slot contiguous (float4 writes)
#define PLD (ND + 4)
#define SMEM_BYTES 33280
__global__ __launch_bounds__(256) void k_main(
    const unsigned short* __restrict__ znb, const float* __restrict__ protos,
    const int* __restrict__ code, const int* __restrict__ validList,
    const int* __restrict__ validCnt,
    float* __restrict__ partialAll, float* __restrict__ partialPos,
    float* __restrict__ plPart)
{
  __shared__ __align__(16) char smem[SMEM_BYTES];
  __shared__ float red3[4];
  const int t = threadIdx.x, lane = t & 63, wid = t >> 6;
  const int bi = blockIdx.x;
  if (bi < PW_BLOCKS) {
    // ---------------- pairwise part ----------------
    unsigned short* aT = (unsigned short*)smem;             // 64x64, 8 KB
    unsigned short* bT = aT + 64 * 64;                      // 128x64, 16 KB
    int* rowIdx = (int*)(bT + 128 * 64);                    // 64
    unsigned char* aoSh = (unsigned char*)(rowIdx + 64);    // 128
    const int ww = wid & 1, wv = wid >> 1;
    const int m = validCnt[0];
    const int nIT = (m + 63) >> 6;
    const int items = nIT * 64;
    const int grp = lane >> 4, cl = lane & 15;
    for (int wi = bi; wi < items; wi += PW_BLOCKS) {
      const int i0 = (wi >> 6) * 64;
      const int jt = wi & 63;
      const int jb = jt * 128;
      __syncthreads();
      if (t < 64) rowIdx[t] = (i0 + t < m) ? validList[i0 + t] : -1;
      if (t < 128) aoSh[t] = (code[jb + t] == NPROTO - 1) ? 1 : 0;
      float4v acc[2][4];
      #pragma unroll
      for (int mi = 0; mi < 2; ++mi)
        #pragma unroll
        for (int nj = 0; nj < 4; ++nj) acc[mi][nj] = (float4v)(0.f);
      for (int kc = 0; kc < 8; ++kc) {
        const int k0 = kc * 64;
        __syncthreads();
        {  // stage A: gathered via validList (64 rows x 8 chunks, 2/thread)
          const int ia = t >> 2;
          const int ri = rowIdx[ia];
          const int srow = (ri < 0) ? 0 : ri;
          #pragma unroll
          for (int h = 0; h < 2; ++h) {
            const int kq = (t & 3) + h * 4;
            const uint4 v = *(const uint4*)(znb + (size_t)srow * ND + k0 + kq * 8);
            *(uint4*)((char*)aT + ia * 128 + ((kq * 16) ^ ((ia & 7) << 4))) = v;
          }
        }
        #pragma unroll
        for (int h = 0; h < 4; ++h) {  // stage B: 128 rows x 8 chunks, 4/thread
          const int f = t + h * 256;
          const int j = f >> 3, kq = f & 7;
          const uint4 v = *(const uint4*)(znb + (size_t)(jb + j) * ND + k0 + kq * 8);
          *(uint4*)((char*)bT + j * 128 + ((kq * 16) ^ ((j & 7) << 4))) = v;
        }
        __syncthreads();
        #pragma unroll
        for (int ks = 0; ks < 2; ++ks) {
          const int kb = ks * 64 + grp * 16;
          short8 af[2], bf[4];
          #pragma unroll
          for (int mi = 0; mi < 2; ++mi) {
            const int rw = wv * 32 + mi * 16 + cl;
            af[mi] = *(const short8*)((char*)aT + rw * 128 + (kb ^ ((rw & 7) << 4)));
          }
          #pragma unroll
          for (int nj = 0; nj < 4; ++nj) {
            const int rw = ww * 64 + nj * 16 + cl;
            bf[nj] = *(const short8*)((char*)bT + rw * 128 + (kb ^ ((rw & 7) << 4)));
          }
          #pragma unroll
          for (int mi = 0; mi < 2; ++mi)
            #pragma unroll
            for (int nj = 0; nj < 4; ++nj)
              acc[mi][nj] = __builtin_amdgcn_mfma_f32_16x16x32_bf16(af[mi], bf[nj], acc[mi][nj], 0, 0, 0);
        }
      }
      // epilogue: exp, diag+pos masks, row sums, DIRECT partial writes
      #pragma unroll
      for (int mi = 0; mi < 2; ++mi) {
        float sA[4] = {0.f, 0.f, 0.f, 0.f}, sP[4] = {0.f, 0.f, 0.f, 0.f};
        int ri[4];
        #pragma unroll
        for (int q = 0; q < 4; ++q) ri[q] = rowIdx[wv * 32 + mi * 16 + grp * 4 + q];
        #pragma unroll
        for (int nj = 0; nj < 4; ++nj) {
          const int jl = ww * 64 + nj * 16 + cl;
          const int jg = jb + jl;
          const float ao = aoSh[jl] ? 1.f : 0.f;
          #pragma unroll
          for (int q = 0; q < 4; ++q) {
            float e = __expf(acc[mi][nj][q] * TINV);
            e = (jg == ri[q]) ? 0.f : e;
            sA[q] += e;
            sP[q] += e * ao;
          }
        }
        #pragma unroll
        for (int q = 0; q < 4; ++q) {
          #pragma unroll
          for (int o = 1; o < 16; o <<= 1) {
            sA[q] += __shfl_xor(sA[q], o);
            sP[q] += __shfl_xor(sP[q], o);
          }
        }
        if (cl == 0) {
          const int slot0 = i0 + wv * 32 + mi * 16 + grp * 4;
          const int jt2 = jt * 2 + ww;
          if (slot0 + 3 < m) {
            *(float4*)&partialAll[(size_t)jt2 * NB + slot0] =
                make_float4(sA[0], sA[1], sA[2], sA[3]);
            *(float4*)&partialPos[(size_t)jt2 * NB + slot0] =
                make_float4(sP[0], sP[1], sP[2], sP[3]);
          } else {
            #pragma unroll
            for (int q = 0; q < 4; ++q) {
              if (slot0 + q < m) {
                partialAll[(size_t)jt2 * NB + slot0 + q] = sA[q];
                partialPos[(size_t)jt2 * NB + slot0 + q] = sP[q];
              }
            }
          }
        }
      }
    }
  } else {
    // ---------------- protoloss part ----------------
    float* pl = (float*)smem;                               // 16 x PLD
    const int pb = bi - PW_BLOCKS;
    for (int i = t; i < NPROTO * ND; i += 256)
      pl[(i >> 9) * PLD + (i & 511)] = protos[i];
    __syncthreads();
    const int p = lane & 15, grp = lane >> 4;
    float lacc = 0.f;
    for (int r = pb * 4 + wid; r < NB; r += PL_BLOCKS * 4) {
      const uint4* zr = (const uint4*)(znb + (size_t)r * ND + grp * 128);
      const float* pbp = &pl[p * PLD + grp * 128];
      float s = 0.f;
      #pragma unroll
      for (int it = 0; it < 16; ++it) {
        const uint4 u = zr[it];
        const float4 p0 = *(const float4*)(pbp + it * 8);
        const float4 p1 = *(const float4*)(pbp + it * 8 + 4);
        s += bflo(u.x)*p0.x + bfhi(u.x)*p0.y + bflo(u.y)*p0.z + bfhi(u.y)*p0.w;
        s += bflo(u.z)*p1.x + bfhi(u.z)*p1.y + bflo(u.w)*p1.z + bfhi(u.w)*p1.w;
      }
      s += __shfl_xor(s, 16);
      s += __shfl_xor(s, 32);
      const float e = __expf(s * TINV);
      float alls = e;
      alls += __shfl_xor(alls, 1);
      alls += __shfl_xor(alls, 2);
      alls += __shfl_xor(alls, 4);
      alls += __shfl_xor(alls, 8);
      const int c = code[r];
      const float pos = __shfl(e, (lane & ~15) | c);
      if (lane == 0) lacc += -logf(pos / fmaxf(alls, 1e-8f) + 1e-8f);
    }
    if (lane == 0) red3[wid] = lacc;
    __syncthreads();
    if (t == 0) plPart[pb] = red3[0] + red3[1] + red3[2] + red3[3];
  }
}

// ---- K4: finalize — 1024 thr, coalesced column reads, split-k halves ------
__global__ __launch_bounds__(1024) void k_final(
    const float* __restrict__ partialAll, const float* __restrict__ partialPos,
    const float* __restrict__ plPart, const int* __restrict__ validCnt,
    float* __restrict__ out)
{
  __shared__ float shA[1024], shP[1024];
  __shared__ float red[16], red2[16];
  const int t = threadIdx.x, lane = t & 63, wid = t >> 6;
  const int m = validCnt[0];
  const int nvalid = (m >= 2) ? m : 0;
  const int slot = t & 511, half = t >> 9;
  float sa = 0.f, sp = 0.f;
  if (slot < nvalid) {
    const int k0 = half * 64;
    #pragma unroll 8
    for (int k = k0; k < k0 + 64; ++k) {
      sa += partialAll[(size_t)k * NB + slot];   // coalesced across threads
      sp += partialPos[(size_t)k * NB + slot];
    }
  }
  shA[t] = sa; shP[t] = sp;
  __syncthreads();
  float s = 0.f;
  if (t < 512 && slot < nvalid) {
    const float A = shA[t] + shA[t + 512];
    const float P = shP[t] + shP[t + 512];
    s = -logf(P / (A + 1e-8f) + 1e-8f);
  }
  float pls = (t < PL_BLOCKS) ? plPart[t] : 0.f;
  #pragma unroll
  for (int o = 32; o > 0; o >>= 1) {
    s += __shfl_xor(s, o);
    pls += __shfl_xor(pls, o);
  }
  if (lane == 0) { red[wid] = s; red2[wid] = pls; }
  __syncthreads();
  if (t == 0) {
    float total = 0.f, plTot = 0.f;
    #pragma unroll
    for (int w = 0; w < 16; ++w) { total += red[w]; plTot += red2[w]; }
    const float proto = plTot / (float)NB;
    float loss = proto;
    if (nvalid > 0) loss = 0.7f * proto + 0.3f * (total / (float)nvalid);
    out[0] = loss;
  }
}

extern "C" void kernel_launch(void* const* d_in, const int* in_sizes, int n_in,
                              void* d_out, int out_size, void* d_ws, size_t ws_size,
                              hipStream_t stream) {
  const float* z = (const float*)d_in[0];
  const float* attr = (const float*)d_in[1];
  unsigned short* znb = (unsigned short*)d_ws;            // NB*ND bf16 (8 MB)
  float* partialSum = (float*)(znb + (size_t)NB * ND);    // [p][b][d] (8 MB)
  // overlay: partialSum is dead after k_protonorm; k_main reuses it
  float* partialAll = partialSum;                         // [128][NB] (4 MB)
  float* partialPos = partialSum + (size_t)128 * NB;      // [128][NB] (4 MB)
  int* validCnt = (int*)(partialSum + (size_t)NBLK * NPROTO * ND);  // 1
  int* code = validCnt + 1;                               // NB
  int* validList = code + NB;                             // NB
  float* protos = (float*)(validList + NB);               // NPROTO*ND
  float* plPart = protos + NPROTO * ND;                   // PL_BLOCKS
  k_norm<<<dim3(NBLK), dim3(512), 0, stream>>>(z, attr, znb, partialSum, code);
  k_protonorm<<<dim3(NPROTO), dim3(512), 0, stream>>>(partialSum, code, protos,
                                                      validList, validCnt);
  k_main<<<dim3(PW_BLOCKS + PL_BLOCKS), dim3(256), 0, stream>>>(
      znb, protos, code, validList, validCnt, partialAll, partialPos, plPart);
  k_final<<<dim3(1), dim3(1024), 0, stream>>>(partialAll, partialPos, plPart,
                                              validCnt, (float*)d_out);
}